// Round 3
// baseline (901.023 us; speedup 1.0000x reference)
//
#include <hip/hip_runtime.h>
#include <hip/hip_bf16.h>
#include <math.h>

#define N_NODES 100000
#define N_EDGES 3200000
#define IN_F 256
#define OUT_F 64
#define LRELU_SLOPE 0.2f
#define XPITCH 264                      // LDS row pitch in bf16 (2-way banks)
#define SCAN_T 1024
#define SCAN_PER 98                     // ceil(100000/1024)

typedef __attribute__((ext_vector_type(8))) short bf16x8;
typedef __attribute__((ext_vector_type(4))) float f32x4;

// ---------------------------------------------------------------------------
// K0: W (256x64 fp32) -> wt (64x256 bf16, transposed). 64 blocks x 256 thr.
// ---------------------------------------------------------------------------
__global__ __launch_bounds__(256) void wt_kernel(
    const float* __restrict__ W, __hip_bfloat16* __restrict__ wt) {
  wt[blockIdx.x * 256 + threadIdx.x] =
      __float2bfloat16(W[threadIdx.x * 64 + blockIdx.x]);
}

// ---------------------------------------------------------------------------
// K1: h = X @ W via bf16 MFMA 16x16x32, fused s_src = h@a[:64] (bf16 store),
// s_dst = h@a[64:] (fp32). 64 rows/block, 4 waves.
// ---------------------------------------------------------------------------
__global__ __launch_bounds__(256) void gemm_h_kernel(
    const float* __restrict__ in, const __hip_bfloat16* __restrict__ wt,
    const float* __restrict__ a, __hip_bfloat16* __restrict__ h,
    __hip_bfloat16* __restrict__ s_src, float* __restrict__ s_dst) {
  __shared__ __hip_bfloat16 xl[64 * XPITCH];    // 33792 B
  const int tid = threadIdx.x;
  const int r0 = blockIdx.x * 64;

#pragma unroll
  for (int i = 0; i < 16; ++i) {
    const int e = i * 256 + tid;        // e in [0,4096)
    const int row = e >> 6, kc = e & 63;
    const int grow = r0 + row;
    float4 v = make_float4(0.f, 0.f, 0.f, 0.f);
    if (grow < N_NODES)
      v = *(const float4*)&in[(size_t)grow * IN_F + kc * 4];
    __hip_bfloat16 b4[4] = {__float2bfloat16(v.x), __float2bfloat16(v.y),
                            __float2bfloat16(v.z), __float2bfloat16(v.w)};
    *(uint2*)&xl[row * XPITCH + kc * 4] = *(uint2*)b4;
  }
  __syncthreads();

  const int w = tid >> 6, lane = tid & 63;
  const int lm = lane & 15, lg = lane >> 4;

  f32x4 acc[4];
#pragma unroll
  for (int ct = 0; ct < 4; ++ct) acc[ct] = (f32x4){0.f, 0.f, 0.f, 0.f};

  const __hip_bfloat16* xbase = &xl[(w * 16 + lm) * XPITCH + lg * 8];
  const __hip_bfloat16* wbase = &wt[(size_t)lm * IN_F + lg * 8];

#pragma unroll
  for (int kt = 0; kt < 8; ++kt) {
    bf16x8 af = *(const bf16x8*)(xbase + kt * 32);
#pragma unroll
    for (int ct = 0; ct < 4; ++ct) {
      bf16x8 bfr = *(const bf16x8*)(wbase + (size_t)ct * 16 * IN_F + kt * 32);
      acc[ct] = __builtin_amdgcn_mfma_f32_16x16x32_bf16(af, bfr, acc[ct],
                                                        0, 0, 0);
    }
  }

  float as[4], ad[4];
#pragma unroll
  for (int ct = 0; ct < 4; ++ct) {
    as[ct] = a[ct * 16 + lm];
    ad[ct] = a[OUT_F + ct * 16 + lm];
  }
#pragma unroll
  for (int reg = 0; reg < 4; ++reg) {
    const int row = r0 + w * 16 + lg * 4 + reg;
    float vs = 0.f, vd = 0.f;
    if (row < N_NODES) {
#pragma unroll
      for (int ct = 0; ct < 4; ++ct) {
        const float v = acc[ct][reg];
        h[(size_t)row * OUT_F + ct * 16 + lm] = __float2bfloat16(v);
        vs += v * as[ct];
        vd += v * ad[ct];
      }
    }
#pragma unroll
    for (int m = 1; m < 16; m <<= 1) {
      vs += __shfl_xor(vs, m);
      vd += __shfl_xor(vd, m);
    }
    if (lm == 0 && row < N_NODES) {
      s_src[row] = __float2bfloat16(vs);
      s_dst[row] = vd;
    }
  }
}

// ---------------------------------------------------------------------------
// K2: per-NODE histogram into A, int4 reads (4 edges/thread).
// ---------------------------------------------------------------------------
__global__ __launch_bounds__(256) void node_hist_kernel(
    const int4* __restrict__ src4, int* __restrict__ A) {
  const int t = blockIdx.x * 256 + threadIdx.x;
  const int4 s = src4[t];
  atomicAdd(&A[s.x], 1);
  atomicAdd(&A[s.y], 1);
  atomicAdd(&A[s.z], 1);
  atomicAdd(&A[s.w], 1);
}

// ---------------------------------------------------------------------------
// K3: deterministic in-place exclusive scan of A (counts -> starts).
// Single block, 1024 threads, 98 elems/thread, two passes over own range.
// ---------------------------------------------------------------------------
__global__ __launch_bounds__(SCAN_T) void scan_kernel(int* __restrict__ A) {
  __shared__ int ts[SCAN_T];
  const int t = threadIdx.x;
  const int o0 = t * SCAN_PER;
  int s = 0;
  for (int k = 0; k < SCAN_PER; ++k) {
    const int o = o0 + k;
    if (o < N_NODES) s += A[o];
  }
  ts[t] = s;
  __syncthreads();
  for (int off = 1; off < SCAN_T; off <<= 1) {
    int tv = (t >= off) ? ts[t - off] : 0;
    __syncthreads();
    ts[t] += tv;
    __syncthreads();
  }
  int base = (t > 0) ? ts[t - 1] : 0;
  for (int k = 0; k < SCAN_PER; ++k) {
    const int o = o0 + k;
    if (o < N_NODES) {
      const int v = A[o];
      A[o] = base;
      base += v;
    }
  }
}

// ---------------------------------------------------------------------------
// K4: scatter dst into per-node segments; A is the cursor. After this
// kernel A[n] == segment end (and == start of n+1, since node-ordered).
// ---------------------------------------------------------------------------
__global__ __launch_bounds__(256) void scatter_kernel(
    const int4* __restrict__ src4, const int4* __restrict__ dst4,
    int* __restrict__ A, int* __restrict__ staged) {
  const int t = blockIdx.x * 256 + threadIdx.x;
  const int4 s = src4[t];
  const int4 d = dst4[t];
  int p;
  p = atomicAdd(&A[s.x], 1); staged[p] = d.x;
  p = atomicAdd(&A[s.y], 1); staged[p] = d.y;
  p = atomicAdd(&A[s.z], 1); staged[p] = d.z;
  p = atomicAdd(&A[s.w], 1); staged[p] = d.w;
}

// ---------------------------------------------------------------------------
// K5: barrier-free, LDS-free aggregation. Wave owns 16 consecutive nodes;
// segment bounds walk A once per node (end of n = start of n+1).
// 8-wide batched gathers for load ILP. Epilogue: out = elu(acc/rowsum).
// ---------------------------------------------------------------------------
__global__ __launch_bounds__(256) void aggregate_kernel(
    const int* __restrict__ A, const int* __restrict__ staged,
    const __hip_bfloat16* __restrict__ s_src, const float* __restrict__ s_dst,
    const __hip_bfloat16* __restrict__ h, float* __restrict__ out) {
  const int tid = threadIdx.x;
  const int lane = tid & 63;
  const int wv = tid >> 6;
  const int n0 = blockIdx.x * 64 + wv * 16;   // wave's first node
  if (n0 >= N_NODES) return;

  int i0 = (n0 > 0) ? A[n0 - 1] : 0;          // start of first node

  for (int j = 0; j < 16; ++j) {
    const int n = n0 + j;
    if (n >= N_NODES) break;
    const int i1 = A[n];                      // end (= start of n+1)
    const float ssn = __bfloat162float(s_src[n]);
    float acc = 0.f, rs = 0.f;
    int i = i0;
    for (; i + 8 <= i1; i += 8) {
      int d[8];
      float sd[8], hv[8];
#pragma unroll
      for (int k = 0; k < 8; ++k) d[k] = staged[i + k];
#pragma unroll
      for (int k = 0; k < 8; ++k) sd[k] = s_dst[d[k]];
#pragma unroll
      for (int k = 0; k < 8; ++k)
        hv[k] = __bfloat162float(h[(size_t)d[k] * OUT_F + lane]);
#pragma unroll
      for (int k = 0; k < 8; ++k) {
        const float sc = ssn + sd[k];
        const float lr = fmaxf(sc, LRELU_SLOPE * sc);
        const float ev = __expf(-lr);
        acc += ev * hv[k];
        rs += ev;
      }
    }
    for (; i < i1; ++i) {
      const int dd = staged[i];
      const float sc = ssn + s_dst[dd];
      const float lr = fmaxf(sc, LRELU_SLOPE * sc);
      const float ev = __expf(-lr);
      acc += ev * __bfloat162float(h[(size_t)dd * OUT_F + lane]);
      rs += ev;
    }
    const float v = acc / rs;
    out[(size_t)n * OUT_F + lane] = v > 0.f ? v : expm1f(v);
    i0 = i1;
  }
}

extern "C" void kernel_launch(void* const* d_in, const int* in_sizes, int n_in,
                              void* d_out, int out_size, void* d_ws, size_t ws_size,
                              hipStream_t stream) {
  const float* in = (const float*)d_in[0];
  const int* edge = (const int*)d_in[1];
  const float* W = (const float*)d_in[2];
  const float* a = (const float*)d_in[3];
  float* out = (float*)d_out;

  const int4* src4 = (const int4*)edge;
  const int4* dst4 = (const int4*)(edge + N_EDGES);

  // workspace (26,632,768 B <= proven-safe 26,639,100 B):
  //   h 12.8M | s_dst 0.4M | staged 12.8M | A 0.4M | wt 32K | s_src 0.2M
  char* p = (char*)d_ws;
  __hip_bfloat16* h = (__hip_bfloat16*)p;  p += (size_t)N_NODES * OUT_F * 2;
  float* s_dst = (float*)p;                p += (size_t)N_NODES * 4;
  int* staged = (int*)p;                   p += (size_t)N_EDGES * 4;
  int* A = (int*)p;                        p += (size_t)N_NODES * 4;
  __hip_bfloat16* wt = (__hip_bfloat16*)p; p += (size_t)OUT_F * IN_F * 2;
  __hip_bfloat16* s_src = (__hip_bfloat16*)p; p += (size_t)N_NODES * 2;

  hipMemsetAsync(A, 0, (size_t)N_NODES * 4, stream);

  wt_kernel<<<OUT_F, 256, 0, stream>>>(W, wt);
  gemm_h_kernel<<<(N_NODES + 63) / 64, 256, 0, stream>>>(in, wt, a, h, s_src,
                                                         s_dst);
  node_hist_kernel<<<N_EDGES / 1024, 256, 0, stream>>>(src4, A);
  scan_kernel<<<1, SCAN_T, 0, stream>>>(A);
  scatter_kernel<<<N_EDGES / 1024, 256, 0, stream>>>(src4, dst4, A, staged);
  aggregate_kernel<<<(N_NODES + 63) / 64, 256, 0, stream>>>(
      A, staged, s_src, s_dst, h, out);
}